// Round 2
// baseline (5735.004 us; speedup 1.0000x reference)
//
#include <hip/hip_runtime.h>

// Problem constants
#define NROW 16384   // B*H*W
#define KC   2048    // n_codes
#define DIM  512     // embedding dim

typedef __attribute__((ext_vector_type(8))) short          short8;
typedef __attribute__((ext_vector_type(8))) unsigned short ushort8;
typedef __attribute__((ext_vector_type(4))) float          floatx4;

// ---------------- helpers ----------------

__device__ __forceinline__ unsigned short f2bf(float f) {
  unsigned int u = __float_as_uint(f);
  u += 0x7fffu + ((u >> 16) & 1u);
  return (unsigned short)(u >> 16);
}
__device__ __forceinline__ float bf2f(unsigned short u) {
  return __uint_as_float(((unsigned int)u) << 16);
}
__device__ __forceinline__ void gload_lds16(const void* g, void* l) {
  __builtin_amdgcn_global_load_lds((const __attribute__((address_space(1))) void*)g,
                                   (__attribute__((address_space(3))) void*)l, 16, 0, 0);
}

// ---------------- K1: codebook row-normalize -> bf16 + csq ----------------
__global__ void k_cbnorm(const float* __restrict__ emb,
                         unsigned short* __restrict__ cb_bf,
                         float* __restrict__ csq) {
  const int k = blockIdx.x;
  const int t = threadIdx.x;        // 256
  const float* row = emb + (size_t)k * DIM;
  float v0 = row[t], v1 = row[t + 256];
  float ss = v0 * v0 + v1 * v1;
#pragma unroll
  for (int o = 32; o; o >>= 1) ss += __shfl_xor(ss, o, 64);
  __shared__ float red[4];
  if ((t & 63) == 0) red[t >> 6] = ss;
  __syncthreads();
  float tot = red[0] + red[1] + red[2] + red[3];
  float r = 1.0f / fmaxf(sqrtf(tot), 1e-12f);
  cb_bf[(size_t)k * DIM + t]       = f2bf(v0 * r);
  cb_bf[(size_t)k * DIM + t + 256] = f2bf(v1 * r);
  if (t == 0) csq[k] = tot * r * r;
}

// ---------------- K2: fused transpose + raw-bf16 + ssq partials ----------------
// z [B,D,HW] fp32 -> zbf [N,D] bf16 (raw, unnormalized), ssq[n] += sum_d z^2
__global__ void k_prep(const float* __restrict__ z,
                       unsigned short* __restrict__ zbf,
                       float* __restrict__ ssq) {
  __shared__ float tile[32][33];
  const int dt = blockIdx.x;   // 0..15
  const int pt = blockIdx.y;   // 0..31
  const int b  = blockIdx.z;   // 0..15
  const int tx = threadIdx.x & 31;
  const int ty = threadIdx.x >> 5;     // 0..7
  const size_t zb = (size_t)b * (DIM * 1024);
#pragma unroll
  for (int i = 0; i < 4; ++i) {
    int d = dt * 32 + ty + i * 8;
    int p = pt * 32 + tx;
    tile[ty + i * 8][tx] = z[zb + (size_t)d * 1024 + p];
  }
  __syncthreads();
#pragma unroll
  for (int i = 0; i < 4; ++i) {
    int p = pt * 32 + ty + i * 8;
    int d = dt * 32 + tx;
    float v = tile[tx][ty + i * 8];
    zbf[(size_t)((b << 10) + p) * DIM + d] = f2bf(v);
    float s = v * v;
#pragma unroll
    for (int o = 16; o; o >>= 1) s += __shfl_xor(s, o, 64);  // within 32-lane half
    if (tx == 0) atomicAdd(&ssq[(b << 10) + p], s);
  }
}

// ---------------- K3: rnorm from ssq ----------------
__global__ void k_rnorm(const float* __restrict__ ssq, float* __restrict__ rnorm) {
  int n = blockIdx.x * 256 + threadIdx.x;
  rnorm[n] = 1.0f / fmaxf(sqrtf(ssq[n]), 1e-12f);
}

// ---------------- K4: bf16 MFMA GEMM -> bf16 logits t = 2*rnorm*dot - csq ----------
// 128x128 tile, BK=64, 4 waves 64x64, 16x16x32 MFMA, XOR-swizzled LDS,
// staging via global_load_lds width=16 (swizzle folded into source addresses).
// Logits stored bf16 in the FIRST 4KB of each row's 8KB fp32 slot (same-row in-place safe).
__global__ __launch_bounds__(256) void k_gemm(const unsigned short* __restrict__ A,
                                              const unsigned short* __restrict__ Bm,
                                              const float* __restrict__ rnorm,
                                              const float* __restrict__ csq,
                                              unsigned short* __restrict__ Tlog) {
  __shared__ alignas(16) unsigned short smA[128 * 64];
  __shared__ alignas(16) unsigned short smB[128 * 64];
  const int tid  = threadIdx.x;
  const int wid  = tid >> 6;
  const int lane = tid & 63;
  const int m0 = blockIdx.x * 128;
  const int n0 = blockIdx.y * 128;
  const int wm = (wid >> 1) * 64;
  const int wn = (wid & 1) * 64;

  floatx4 acc[4][4];
  const floatx4 z4 = {0.f, 0.f, 0.f, 0.f};
#pragma unroll
  for (int mi = 0; mi < 4; ++mi)
#pragma unroll
    for (int ni = 0; ni < 4; ++ni) acc[mi][ni] = z4;

  const int srow = lane >> 3;   // row within an 8-row issue
  const int spb  = lane & 7;    // physical 16B block within row

  for (int kt = 0; kt < 8; ++kt) {
    const int kbase = kt * 64;
#pragma unroll
    for (int i = 0; i < 4; ++i) {
      const int issue = wid * 4 + i;        // 0..15
      const int row   = issue * 8 + srow;   // 0..127
      const int lb    = spb ^ (row & 7);    // logical block this slot holds
      gload_lds16(A  + (size_t)(m0 + row) * DIM + kbase + lb * 8, smA + issue * 512);
      gload_lds16(Bm + (size_t)(n0 + row) * DIM + kbase + lb * 8, smB + issue * 512);
    }
    __syncthreads();
#pragma unroll
    for (int kk = 0; kk < 2; ++kk) {
      const int q   = lane >> 4;
      const int mr  = lane & 15;
      const int lbq = kk * 4 + q;
      short8 af[4], bfr[4];
#pragma unroll
      for (int mi = 0; mi < 4; ++mi) {
        int row = wm + mi * 16 + mr;
        int pb  = lbq ^ (row & 7);
        af[mi] = *(const short8*)&smA[row * 64 + pb * 8];
      }
#pragma unroll
      for (int ni = 0; ni < 4; ++ni) {
        int row = wn + ni * 16 + mr;
        int pb  = lbq ^ (row & 7);
        bfr[ni] = *(const short8*)&smB[row * 64 + pb * 8];
      }
#pragma unroll
      for (int mi = 0; mi < 4; ++mi)
#pragma unroll
        for (int ni = 0; ni < 4; ++ni)
          acc[mi][ni] = __builtin_amdgcn_mfma_f32_16x16x32_bf16(af[mi], bfr[ni], acc[mi][ni], 0, 0, 0);
    }
    __syncthreads();
  }

  // epilogue: C/D layout col = lane&15, row = (lane>>4)*4 + reg
  const int col = lane & 15;
  const int rq  = (lane >> 4) * 4;
#pragma unroll
  for (int mi = 0; mi < 4; ++mi)
#pragma unroll
    for (int r = 0; r < 4; ++r) {
      const int row = m0 + wm + mi * 16 + rq + r;
      const float rn2 = 2.0f * rnorm[row];
      size_t slot = (size_t)row * 4096;   // ushort slot stride = 8KB
#pragma unroll
      for (int ni = 0; ni < 4; ++ni) {
        int c = n0 + wn + ni * 16 + col;
        Tlog[slot + c] = f2bf(rn2 * acc[mi][ni][r] - csq[c]);
      }
    }
}

// ---------------- K5: softmax (bf16 logits -> fp32 probs, same-row in-place) ------
#define MARGIN_T 3.0e-2f   // >= 2*(bf16 dot err 7.8e-3 + bf16 store err 2.5e-3)

__global__ void k_softmax(float* __restrict__ S,
                          int* __restrict__ cand_cnt, int* __restrict__ cand_list) {
  const int n = blockIdx.x;
  const int t = threadIdx.x;  // 256
  const unsigned short* ur = (const unsigned short*)S + (size_t)n * 4096;
  float* frow = S + (size_t)n * KC;
  ushort8 uv = *(const ushort8*)(ur + t * 8);
  float tv[8];
  float mx = -3.4e38f;
#pragma unroll
  for (int j = 0; j < 8; ++j) {
    tv[j] = bf2f(uv[j]);
    mx = fmaxf(mx, tv[j]);
  }
#pragma unroll
  for (int o = 32; o; o >>= 1) mx = fmaxf(mx, __shfl_xor(mx, o, 64));
  __shared__ float redm[4];
  __shared__ float redsum[4];
  __shared__ int   s_cnt;
  __shared__ int   s_list[16];
  if (t == 0) s_cnt = 0;
  if ((t & 63) == 0) redm[t >> 6] = mx;
  __syncthreads();
  const float MX = fmaxf(fmaxf(redm[0], redm[1]), fmaxf(redm[2], redm[3]));
  float ev[8];
  float sum = 0.f;
#pragma unroll
  for (int j = 0; j < 8; ++j) {
    if (tv[j] >= MX - MARGIN_T) {
      int p = atomicAdd(&s_cnt, 1);
      if (p < 16) s_list[p] = t * 8 + j;
    }
    ev[j] = __expf(tv[j] - MX);
    sum += ev[j];
  }
#pragma unroll
  for (int o = 32; o; o >>= 1) sum += __shfl_xor(sum, o, 64);
  if ((t & 63) == 0) redsum[t >> 6] = sum;
  __syncthreads();
  const float inv = 1.0f / (redsum[0] + redsum[1] + redsum[2] + redsum[3]);
  floatx4 w0 = {ev[0] * inv, ev[1] * inv, ev[2] * inv, ev[3] * inv};
  floatx4 w1 = {ev[4] * inv, ev[5] * inv, ev[6] * inv, ev[7] * inv};
  *(floatx4*)(frow + t * 8)     = w0;
  *(floatx4*)(frow + t * 8 + 4) = w1;
  if (t < 16 && t < s_cnt) cand_list[n * 16 + t] = s_list[t];
  if (t == 0) cand_cnt[n] = (s_cnt > 16) ? -1 : s_cnt;
}

// ---------------- K6: exact fp64 argmin among candidates (reads RAW z) -----------
__global__ void k_fixup(const float* __restrict__ z, const float* __restrict__ emb,
                        const int* __restrict__ cand_cnt, const int* __restrict__ cand_list,
                        int* __restrict__ idx) {
  const int n = blockIdx.x;
  const int l = threadIdx.x;  // 64
  const int c = cand_cnt[n];
  if (c == 1) {
    if (l == 0) idx[n] = cand_list[n * 16];
    return;
  }
  const int b = n >> 10, p = n & 1023;
  const float* zbase = z + ((size_t)b * DIM) * 1024 + p;   // element d at zbase[d*1024]
  double zs = 0.0;
  for (int d = l; d < DIM; d += 64) { double v = zbase[(size_t)d << 10]; zs += v * v; }
#pragma unroll
  for (int o = 32; o; o >>= 1) zs += __shfl_xor(zs, o, 64);
  double zn = fmax(sqrt(zs), 1e-12);
  double best = 1e300;
  int bestk = 0x7fffffff;
  const int m = (c < 0) ? KC : c;
  for (int ci = 0; ci < m; ++ci) {
    int k = (c < 0) ? ci : cand_list[n * 16 + ci];
    const float* er = emb + (size_t)k * DIM;
    double cs = 0.0, dot = 0.0;
    for (int d = l; d < DIM; d += 64) {
      double e = er[d], zv = zbase[(size_t)d << 10];
      cs += e * e; dot += zv * e;
    }
#pragma unroll
    for (int o = 32; o; o >>= 1) { cs += __shfl_xor(cs, o, 64); dot += __shfl_xor(dot, o, 64); }
    double cn = fmax(sqrt(cs), 1e-12);
    double score = cs / (cn * cn) - 2.0 * dot / (zn * cn);
    if (score < best || (score == best && k < bestk)) { best = score; bestk = k; }
  }
  if (l == 0) idx[n] = bestk;
}

// ---------------- K7: commitment-loss partials + EMA stats (bf16 source) --------
__global__ void k_stats(const unsigned short* __restrict__ zbf, const float* __restrict__ rnorm,
                        const int* __restrict__ idx, float* __restrict__ enc_sum,
                        float* __restrict__ n_total, double* __restrict__ cl_part) {
  const int n = blockIdx.x;
  const int t = threadIdx.x;  // 256
  const int j = idx[n];
  const float rn = rnorm[n], rj = rnorm[j];
  const unsigned int zn2 = *(const unsigned int*)(zbf + (size_t)n * DIM + t * 2);
  const unsigned int zj2 = *(const unsigned int*)(zbf + (size_t)j * DIM + t * 2);
  float zv0 = bf2f((unsigned short)(zn2 & 0xffff)) * rn;
  float zv1 = bf2f((unsigned short)(zn2 >> 16)) * rn;
  float ev0 = bf2f((unsigned short)(zj2 & 0xffff)) * rj;
  float ev1 = bf2f((unsigned short)(zj2 >> 16)) * rj;
  float d0 = zv0 - ev0, d1 = zv1 - ev1;
  double cl = (double)d0 * d0 + (double)d1 * d1;
  atomicAdd(&enc_sum[(size_t)j * DIM + t * 2],     zv0);
  atomicAdd(&enc_sum[(size_t)j * DIM + t * 2 + 1], zv1);
#pragma unroll
  for (int o = 32; o; o >>= 1) cl += __shfl_xor(cl, o, 64);
  __shared__ double red[4];
  if ((t & 63) == 0) red[t >> 6] = cl;
  __syncthreads();
  if (t == 0) {
    cl_part[n] = red[0] + red[1] + red[2] + red[3];
    atomicAdd(&n_total[j], 1.0f);
  }
}

// ---------------- K8: N_new + n = sum(N_new) ----------------
__global__ void k_nnew(const float* __restrict__ Nb, const float* __restrict__ nt,
                       float* __restrict__ outN, double* __restrict__ nw) {
  const int t = threadIdx.x;  // 256
  double s = 0.0;
#pragma unroll
  for (int i = 0; i < 8; ++i) {
    int k = t + i * 256;
    float v = 0.99f * Nb[k] + 0.01f * nt[k];
    outN[k] = v;
    s += (double)v;
  }
#pragma unroll
  for (int o = 32; o; o >>= 1) s += __shfl_xor(s, o, 64);
  __shared__ double red[4];
  if ((t & 63) == 0) red[t >> 6] = s;
  __syncthreads();
  if (t == 0) nw[0] = red[0] + red[1] + red[2] + red[3];
}

// ---------------- K9: fused z_avg_new + embeddings_new + |.| partials ------------
__global__ void k_zavg_emb(const float* __restrict__ za, const float* __restrict__ es,
                           const float* __restrict__ Nn, const double* __restrict__ nw,
                           float* __restrict__ outz, float* __restrict__ oute,
                           double* __restrict__ cbs_part) {
  const int t = threadIdx.x;
  const int i = blockIdx.x * 256 + t;
  const int k = i >> 9;
  const float zv = 0.99f * za[i] + 0.01f * es[i];
  outz[i] = zv;
  const float nv = (float)nw[0];
  const float w = (Nn[k] + 1e-5f) / (nv + 0.02048f) * nv;
  const float e = zv / w;
  oute[i] = e;
  double a = (double)fabsf(e);
#pragma unroll
  for (int o = 32; o; o >>= 1) a += __shfl_xor(a, o, 64);
  __shared__ double red[4];
  if ((t & 63) == 0) red[t >> 6] = a;
  __syncthreads();
  if (t == 0) cbs_part[blockIdx.x] = red[0] + red[1] + red[2] + red[3];
}

// ---------------- K10: q gather ----------------
__global__ void k_q(const unsigned short* __restrict__ zbf, const float* __restrict__ rnorm,
                    const int* __restrict__ idx, float* __restrict__ q) {
  const int o = blockIdx.x * 256 + threadIdx.x;
  const int b = o >> 19;
  const int d = (o >> 10) & 511;
  const int p = o & 1023;
  const int j = idx[(b << 10) + p];
  q[o] = bf2f(zbf[(size_t)j * DIM + d]) * rnorm[j];
}

// ---------------- K11: final scalar reductions ----------------
__global__ void k_final(const double* __restrict__ cl_part, const double* __restrict__ cbs_part,
                        float* __restrict__ out) {
  const int t = threadIdx.x;  // 256
  double cl = 0.0, cb = 0.0;
  for (int i = t; i < NROW; i += 256) cl += cl_part[i];
  for (int i = t; i < 4096; i += 256) cb += cbs_part[i];
#pragma unroll
  for (int o = 32; o; o >>= 1) { cl += __shfl_xor(cl, o, 64); cb += __shfl_xor(cb, o, 64); }
  __shared__ double redc[4], redb[4];
  if ((t & 63) == 0) { redc[t >> 6] = cl; redb[t >> 6] = cb; }
  __syncthreads();
  if (t == 0) {
    double clm = (redc[0] + redc[1] + redc[2] + redc[3]) / 8388608.0;
    double cbs = redb[0] + redb[1] + redb[2] + redb[3];
    out[41943040] = (float)clm;
    out[41943041] = (float)(0.25 * clm);
    out[41943042] = (float)cbs;
  }
}

// ---------------- launcher ----------------
extern "C" void kernel_launch(void* const* d_in, const int* in_sizes, int n_in,
                              void* d_out, int out_size, void* d_ws, size_t ws_size,
                              hipStream_t stream) {
  const float* z   = (const float*)d_in[0];
  const float* emb = (const float*)d_in[1];
  const float* Nb  = (const float*)d_in[2];
  const float* za  = (const float*)d_in[3];
  float* out = (float*)d_out;
  char*  ws  = (char*)d_ws;

  // workspace layout (bytes)
  unsigned short* zbf       = (unsigned short*)(ws + 0);        // 16777216
  float*          rnorm     = (float*)(ws + 16777216);          // 65536
  unsigned short* cb_bf     = (unsigned short*)(ws + 16842752); // 2097152
  float*          csq       = (float*)(ws + 18939904);          // 8192
  int*            idx       = (int*)(ws + 18948096);            // 65536
  int*            cand_cnt  = (int*)(ws + 19013632);            // 65536
  int*            cand_list = (int*)(ws + 19079168);            // 1048576
  double*         cl_part   = (double*)(ws + 20127744);         // 131072
  double*         cbs_part  = (double*)(ws + 20258816);         // 32768
  // zero-initialized block:
  float*          ssq       = (float*)(ws + 20291584);          // 65536
  float*          enc_sum   = (float*)(ws + 20357120);          // 4194304
  float*          n_total   = (float*)(ws + 24551424);          // 8192
  double*         nw        = (double*)(ws + 24559616);         // 8

  // d_out regions (floats): q[0..8388608), dp[8388608..41943040),
  // scalars[41943040..3), emb_new, N_new, z_avg_new
  float* S        = out + 8388608;
  float* out_emb  = out + 41943043;
  float* out_N    = out + 42991619;
  float* out_zav  = out + 42993667;

  hipMemsetAsync(ws + 20291584, 0, 4268032, stream);  // ssq + enc_sum + n_total

  k_cbnorm  <<<KC, 256, 0, stream>>>(emb, cb_bf, csq);
  k_prep    <<<dim3(16, 32, 16), 256, 0, stream>>>(z, zbf, ssq);
  k_rnorm   <<<64, 256, 0, stream>>>(ssq, rnorm);
  k_gemm    <<<dim3(NROW / 128, KC / 128), 256, 0, stream>>>(zbf, cb_bf, rnorm, csq,
                                                             (unsigned short*)S);
  k_softmax <<<NROW, 256, 0, stream>>>(S, cand_cnt, cand_list);
  k_fixup   <<<NROW, 64, 0, stream>>>(z, emb, cand_cnt, cand_list, idx);
  k_stats   <<<NROW, 256, 0, stream>>>(zbf, rnorm, idx, enc_sum, n_total, cl_part);
  k_nnew    <<<1, 256, 0, stream>>>(Nb, n_total, out_N, nw);
  k_zavg_emb<<<4096, 256, 0, stream>>>(za, enc_sum, out_N, nw, out_zav, out_emb, cbs_part);
  k_q       <<<32768, 256, 0, stream>>>(zbf, rnorm, idx, out);
  k_final   <<<1, 256, 0, stream>>>(cl_part, cbs_part, out);
}

// Round 3
// 4237.746 us; speedup vs baseline: 1.3533x; 1.3533x over previous
//
#include <hip/hip_runtime.h>

// Problem constants
#define NROW 16384   // B*H*W
#define KC   2048    // n_codes
#define DIM  512     // embedding dim

typedef __attribute__((ext_vector_type(8))) short          short8;
typedef __attribute__((ext_vector_type(8))) unsigned short ushort8;
typedef __attribute__((ext_vector_type(4))) float          floatx4;

// ---------------- helpers ----------------

__device__ __forceinline__ unsigned short f2bf(float f) {
  unsigned int u = __float_as_uint(f);
  u += 0x7fffu + ((u >> 16) & 1u);
  return (unsigned short)(u >> 16);
}
__device__ __forceinline__ float bf2f(unsigned short u) {
  return __uint_as_float(((unsigned int)u) << 16);
}
__device__ __forceinline__ void gload_lds16(const void* g, void* l) {
  __builtin_amdgcn_global_load_lds((const __attribute__((address_space(1))) void*)g,
                                   (__attribute__((address_space(3))) void*)l, 16, 0, 0);
}

// ---------------- K1: codebook row-normalize -> bf16 + csq ----------------
__global__ void k_cbnorm(const float* __restrict__ emb,
                         unsigned short* __restrict__ cb_bf,
                         float* __restrict__ csq) {
  const int k = blockIdx.x;
  const int t = threadIdx.x;        // 256
  const float* row = emb + (size_t)k * DIM;
  float v0 = row[t], v1 = row[t + 256];
  float ss = v0 * v0 + v1 * v1;
#pragma unroll
  for (int o = 32; o; o >>= 1) ss += __shfl_xor(ss, o, 64);
  __shared__ float red[4];
  if ((t & 63) == 0) red[t >> 6] = ss;
  __syncthreads();
  float tot = red[0] + red[1] + red[2] + red[3];
  float r = 1.0f / fmaxf(sqrtf(tot), 1e-12f);
  cb_bf[(size_t)k * DIM + t]       = f2bf(v0 * r);
  cb_bf[(size_t)k * DIM + t + 256] = f2bf(v1 * r);
  if (t == 0) csq[k] = tot * r * r;
}

// ---------------- K2: fused transpose -> flatT fp32 + zbf bf16 + ssq partials ----
// z [B,D,HW] fp32 -> flatT [N,D] fp32 (raw), zbf [N,D] bf16 (raw), ssq[n]+=sum z^2
__global__ void k_prep(const float* __restrict__ z,
                       float* __restrict__ flatT,
                       unsigned short* __restrict__ zbf,
                       float* __restrict__ ssq) {
  __shared__ float tile[32][33];
  const int dt = blockIdx.x;   // 0..15
  const int pt = blockIdx.y;   // 0..31
  const int b  = blockIdx.z;   // 0..15
  const int tx = threadIdx.x & 31;
  const int ty = threadIdx.x >> 5;     // 0..7
  const size_t zb = (size_t)b * (DIM * 1024);
#pragma unroll
  for (int i = 0; i < 4; ++i) {
    int d = dt * 32 + ty + i * 8;
    int p = pt * 32 + tx;
    tile[ty + i * 8][tx] = z[zb + (size_t)d * 1024 + p];
  }
  __syncthreads();
#pragma unroll
  for (int i = 0; i < 4; ++i) {
    int p = pt * 32 + ty + i * 8;
    int d = dt * 32 + tx;
    float v = tile[tx][ty + i * 8];
    size_t off = (size_t)((b << 10) + p) * DIM + d;
    flatT[off] = v;
    zbf[off]   = f2bf(v);
    float s = v * v;
#pragma unroll
    for (int o = 16; o; o >>= 1) s += __shfl_xor(s, o, 64);  // within 32-lane half
    if (tx == 0) atomicAdd(&ssq[(b << 10) + p], s);
  }
}

// ---------------- K3: rnorm from ssq ----------------
__global__ void k_rnorm(const float* __restrict__ ssq, float* __restrict__ rnorm) {
  int n = blockIdx.x * 256 + threadIdx.x;
  rnorm[n] = 1.0f / fmaxf(sqrtf(ssq[n]), 1e-12f);
}

// ---------------- K4: bf16 MFMA GEMM -> bf16 logits t = 2*rnorm*dot - csq ----------
__global__ __launch_bounds__(256) void k_gemm(const unsigned short* __restrict__ A,
                                              const unsigned short* __restrict__ Bm,
                                              const float* __restrict__ rnorm,
                                              const float* __restrict__ csq,
                                              unsigned short* __restrict__ Tlog) {
  __shared__ alignas(16) unsigned short smA[128 * 64];
  __shared__ alignas(16) unsigned short smB[128 * 64];
  const int tid  = threadIdx.x;
  const int wid  = tid >> 6;
  const int lane = tid & 63;
  const int m0 = blockIdx.x * 128;
  const int n0 = blockIdx.y * 128;
  const int wm = (wid >> 1) * 64;
  const int wn = (wid & 1) * 64;

  floatx4 acc[4][4];
  const floatx4 z4 = {0.f, 0.f, 0.f, 0.f};
#pragma unroll
  for (int mi = 0; mi < 4; ++mi)
#pragma unroll
    for (int ni = 0; ni < 4; ++ni) acc[mi][ni] = z4;

  const int srow = lane >> 3;   // row within an 8-row issue
  const int spb  = lane & 7;    // physical 16B block within row

  for (int kt = 0; kt < 8; ++kt) {
    const int kbase = kt * 64;
#pragma unroll
    for (int i = 0; i < 4; ++i) {
      const int issue = wid * 4 + i;        // 0..15
      const int row   = issue * 8 + srow;   // 0..127
      const int lb    = spb ^ (row & 7);    // logical block this slot holds
      gload_lds16(A  + (size_t)(m0 + row) * DIM + kbase + lb * 8, smA + issue * 512);
      gload_lds16(Bm + (size_t)(n0 + row) * DIM + kbase + lb * 8, smB + issue * 512);
    }
    __syncthreads();
#pragma unroll
    for (int kk = 0; kk < 2; ++kk) {
      const int q   = lane >> 4;
      const int mr  = lane & 15;
      const int lbq = kk * 4 + q;
      short8 af[4], bfr[4];
#pragma unroll
      for (int mi = 0; mi < 4; ++mi) {
        int row = wm + mi * 16 + mr;
        int pb  = lbq ^ (row & 7);
        af[mi] = *(const short8*)&smA[row * 64 + pb * 8];
      }
#pragma unroll
      for (int ni = 0; ni < 4; ++ni) {
        int row = wn + ni * 16 + mr;
        int pb  = lbq ^ (row & 7);
        bfr[ni] = *(const short8*)&smB[row * 64 + pb * 8];
      }
#pragma unroll
      for (int mi = 0; mi < 4; ++mi)
#pragma unroll
        for (int ni = 0; ni < 4; ++ni)
          acc[mi][ni] = __builtin_amdgcn_mfma_f32_16x16x32_bf16(af[mi], bfr[ni], acc[mi][ni], 0, 0, 0);
    }
    __syncthreads();
  }

  const int col = lane & 15;
  const int rq  = (lane >> 4) * 4;
#pragma unroll
  for (int mi = 0; mi < 4; ++mi)
#pragma unroll
    for (int r = 0; r < 4; ++r) {
      const int row = m0 + wm + mi * 16 + rq + r;
      const float rn2 = 2.0f * rnorm[row];
      size_t slot = (size_t)row * 4096;   // ushort slot stride = 8KB
#pragma unroll
      for (int ni = 0; ni < 4; ++ni) {
        int c = n0 + wn + ni * 16 + col;
        Tlog[slot + c] = f2bf(rn2 * acc[mi][ni][r] - csq[c]);
      }
    }
}

// ---------------- K5: softmax (bf16 logits -> fp32 probs, same-row in-place) ------
#define MARGIN_T 3.0e-2f   // >= 2*(bf16 dot err 7.8e-3 + bf16 store err 2.5e-3)

__global__ void k_softmax(float* __restrict__ S,
                          int* __restrict__ cand_cnt, int* __restrict__ cand_list) {
  const int n = blockIdx.x;
  const int t = threadIdx.x;  // 256
  const unsigned short* ur = (const unsigned short*)S + (size_t)n * 4096;
  float* frow = S + (size_t)n * KC;
  ushort8 uv = *(const ushort8*)(ur + t * 8);
  float tv[8];
  float mx = -3.4e38f;
#pragma unroll
  for (int j = 0; j < 8; ++j) {
    tv[j] = bf2f(uv[j]);
    mx = fmaxf(mx, tv[j]);
  }
#pragma unroll
  for (int o = 32; o; o >>= 1) mx = fmaxf(mx, __shfl_xor(mx, o, 64));
  __shared__ float redm[4];
  __shared__ float redsum[4];
  __shared__ int   s_cnt;
  __shared__ int   s_list[16];
  if (t == 0) s_cnt = 0;
  if ((t & 63) == 0) redm[t >> 6] = mx;
  __syncthreads();
  const float MX = fmaxf(fmaxf(redm[0], redm[1]), fmaxf(redm[2], redm[3]));
  float ev[8];
  float sum = 0.f;
#pragma unroll
  for (int j = 0; j < 8; ++j) {
    if (tv[j] >= MX - MARGIN_T) {
      int p = atomicAdd(&s_cnt, 1);
      if (p < 16) s_list[p] = t * 8 + j;
    }
    ev[j] = __expf(tv[j] - MX);
    sum += ev[j];
  }
#pragma unroll
  for (int o = 32; o; o >>= 1) sum += __shfl_xor(sum, o, 64);
  if ((t & 63) == 0) redsum[t >> 6] = sum;
  __syncthreads();
  const float inv = 1.0f / (redsum[0] + redsum[1] + redsum[2] + redsum[3]);
  floatx4 w0 = {ev[0] * inv, ev[1] * inv, ev[2] * inv, ev[3] * inv};
  floatx4 w1 = {ev[4] * inv, ev[5] * inv, ev[6] * inv, ev[7] * inv};
  *(floatx4*)(frow + t * 8)     = w0;
  *(floatx4*)(frow + t * 8 + 4) = w1;
  if (t < 16 && t < s_cnt) cand_list[n * 16 + t] = s_list[t];
  if (t == 0) cand_cnt[n] = (s_cnt > 16) ? -1 : s_cnt;
}

// ---------------- K6: exact fp64 argmin among candidates (contiguous flatT) ------
__global__ void k_fixup(const float* __restrict__ flatT, const float* __restrict__ emb,
                        const int* __restrict__ cand_cnt, const int* __restrict__ cand_list,
                        int* __restrict__ idx) {
  const int n = blockIdx.x;
  const int l = threadIdx.x;  // 64
  const int c = cand_cnt[n];
  if (c == 1) {
    if (l == 0) idx[n] = cand_list[n * 16];
    return;
  }
  const float* zr = flatT + (size_t)n * DIM;
  double zs = 0.0;
  for (int d = l; d < DIM; d += 64) { double v = zr[d]; zs += v * v; }
#pragma unroll
  for (int o = 32; o; o >>= 1) zs += __shfl_xor(zs, o, 64);
  double zn = fmax(sqrt(zs), 1e-12);
  double best = 1e300;
  int bestk = 0x7fffffff;
  const int m = (c < 0) ? KC : c;
  for (int ci = 0; ci < m; ++ci) {
    int k = (c < 0) ? ci : cand_list[n * 16 + ci];
    const float* er = emb + (size_t)k * DIM;
    double cs = 0.0, dot = 0.0;
    for (int d = l; d < DIM; d += 64) {
      double e = er[d], zv = zr[d];
      cs += e * e; dot += zv * e;
    }
#pragma unroll
    for (int o = 32; o; o >>= 1) { cs += __shfl_xor(cs, o, 64); dot += __shfl_xor(dot, o, 64); }
    double cn = fmax(sqrt(cs), 1e-12);
    double score = cs / (cn * cn) - 2.0 * dot / (zn * cn);
    if (score < best || (score == best && k < bestk)) { best = score; bestk = k; }
  }
  if (l == 0) idx[n] = bestk;
}

// ---------------- K7: commitment-loss partials + EMA stats (bf16 source) --------
__global__ void k_stats(const unsigned short* __restrict__ zbf, const float* __restrict__ rnorm,
                        const int* __restrict__ idx, float* __restrict__ enc_sum,
                        float* __restrict__ n_total, double* __restrict__ cl_part) {
  const int n = blockIdx.x;
  const int t = threadIdx.x;  // 256
  const int j = idx[n];
  const float rn = rnorm[n], rj = rnorm[j];
  const unsigned int zn2 = *(const unsigned int*)(zbf + (size_t)n * DIM + t * 2);
  const unsigned int zj2 = *(const unsigned int*)(zbf + (size_t)j * DIM + t * 2);
  float zv0 = bf2f((unsigned short)(zn2 & 0xffff)) * rn;
  float zv1 = bf2f((unsigned short)(zn2 >> 16)) * rn;
  float ev0 = bf2f((unsigned short)(zj2 & 0xffff)) * rj;
  float ev1 = bf2f((unsigned short)(zj2 >> 16)) * rj;
  float d0 = zv0 - ev0, d1 = zv1 - ev1;
  double cl = (double)d0 * d0 + (double)d1 * d1;
  atomicAdd(&enc_sum[(size_t)j * DIM + t * 2],     zv0);
  atomicAdd(&enc_sum[(size_t)j * DIM + t * 2 + 1], zv1);
#pragma unroll
  for (int o = 32; o; o >>= 1) cl += __shfl_xor(cl, o, 64);
  __shared__ double red[4];
  if ((t & 63) == 0) red[t >> 6] = cl;
  __syncthreads();
  if (t == 0) {
    cl_part[n] = red[0] + red[1] + red[2] + red[3];
    atomicAdd(&n_total[j], 1.0f);
  }
}

// ---------------- K8: N_new + n = sum(N_new) ----------------
__global__ void k_nnew(const float* __restrict__ Nb, const float* __restrict__ nt,
                       float* __restrict__ outN, double* __restrict__ nw) {
  const int t = threadIdx.x;  // 256
  double s = 0.0;
#pragma unroll
  for (int i = 0; i < 8; ++i) {
    int k = t + i * 256;
    float v = 0.99f * Nb[k] + 0.01f * nt[k];
    outN[k] = v;
    s += (double)v;
  }
#pragma unroll
  for (int o = 32; o; o >>= 1) s += __shfl_xor(s, o, 64);
  __shared__ double red[4];
  if ((t & 63) == 0) red[t >> 6] = s;
  __syncthreads();
  if (t == 0) nw[0] = red[0] + red[1] + red[2] + red[3];
}

// ---------------- K9: fused z_avg_new + embeddings_new + |.| partials ------------
__global__ void k_zavg_emb(const float* __restrict__ za, const float* __restrict__ es,
                           const float* __restrict__ Nn, const double* __restrict__ nw,
                           float* __restrict__ outz, float* __restrict__ oute,
                           double* __restrict__ cbs_part) {
  const int t = threadIdx.x;
  const int i = blockIdx.x * 256 + t;
  const int k = i >> 9;
  const float zv = 0.99f * za[i] + 0.01f * es[i];
  outz[i] = zv;
  const float nv = (float)nw[0];
  const float w = (Nn[k] + 1e-5f) / (nv + 0.02048f) * nv;
  const float e = zv / w;
  oute[i] = e;
  double a = (double)fabsf(e);
#pragma unroll
  for (int o = 32; o; o >>= 1) a += __shfl_xor(a, o, 64);
  __shared__ double red[4];
  if ((t & 63) == 0) red[t >> 6] = a;
  __syncthreads();
  if (t == 0) cbs_part[blockIdx.x] = red[0] + red[1] + red[2] + red[3];
}

// ---------------- K10: q gather ----------------
__global__ void k_q(const unsigned short* __restrict__ zbf, const float* __restrict__ rnorm,
                    const int* __restrict__ idx, float* __restrict__ q) {
  const int o = blockIdx.x * 256 + threadIdx.x;
  const int b = o >> 19;
  const int d = (o >> 10) & 511;
  const int p = o & 1023;
  const int j = idx[(b << 10) + p];
  q[o] = bf2f(zbf[(size_t)j * DIM + d]) * rnorm[j];
}

// ---------------- K11: final scalar reductions ----------------
__global__ void k_final(const double* __restrict__ cl_part, const double* __restrict__ cbs_part,
                        float* __restrict__ out) {
  const int t = threadIdx.x;  // 256
  double cl = 0.0, cb = 0.0;
  for (int i = t; i < NROW; i += 256) cl += cl_part[i];
  for (int i = t; i < 4096; i += 256) cb += cbs_part[i];
#pragma unroll
  for (int o = 32; o; o >>= 1) { cl += __shfl_xor(cl, o, 64); cb += __shfl_xor(cb, o, 64); }
  __shared__ double redc[4], redb[4];
  if ((t & 63) == 0) { redc[t >> 6] = cl; redb[t >> 6] = cb; }
  __syncthreads();
  if (t == 0) {
    double clm = (redc[0] + redc[1] + redc[2] + redc[3]) / 8388608.0;
    double cbs = redb[0] + redb[1] + redb[2] + redb[3];
    out[41943040] = (float)clm;
    out[41943041] = (float)(0.25 * clm);
    out[41943042] = (float)cbs;
  }
}

// ---------------- launcher ----------------
extern "C" void kernel_launch(void* const* d_in, const int* in_sizes, int n_in,
                              void* d_out, int out_size, void* d_ws, size_t ws_size,
                              hipStream_t stream) {
  const float* z   = (const float*)d_in[0];
  const float* emb = (const float*)d_in[1];
  const float* Nb  = (const float*)d_in[2];
  const float* za  = (const float*)d_in[3];
  float* out = (float*)d_out;
  char*  ws  = (char*)d_ws;

  // workspace layout (bytes)
  unsigned short* zbf       = (unsigned short*)(ws + 0);        // 16777216
  float*          rnorm     = (float*)(ws + 16777216);          // 65536
  unsigned short* cb_bf     = (unsigned short*)(ws + 16842752); // 2097152
  float*          csq       = (float*)(ws + 18939904);          // 8192
  int*            idx       = (int*)(ws + 18948096);            // 65536
  int*            cand_cnt  = (int*)(ws + 19013632);            // 65536
  int*            cand_list = (int*)(ws + 19079168);            // 1048576
  double*         cl_part   = (double*)(ws + 20127744);         // 131072
  double*         cbs_part  = (double*)(ws + 20258816);         // 32768
  // zero-initialized block:
  float*          ssq       = (float*)(ws + 20291584);          // 65536
  float*          enc_sum   = (float*)(ws + 20357120);          // 4194304
  float*          n_total   = (float*)(ws + 24551424);          // 8192
  double*         nw        = (double*)(ws + 24559616);         // 8

  // d_out regions (floats): q[0..8388608) — used as flatT fp32 scratch until k_q,
  // dp[8388608..41943040), scalars[41943040..3), emb_new, N_new, z_avg_new
  float* flatT    = out;              // fp32 [N, D] scratch, overwritten by k_q last
  float* S        = out + 8388608;
  float* out_emb  = out + 41943043;
  float* out_N    = out + 42991619;
  float* out_zav  = out + 42993667;

  hipMemsetAsync(ws + 20291584, 0, 4268032, stream);  // ssq + enc_sum + n_total

  k_cbnorm  <<<KC, 256, 0, stream>>>(emb, cb_bf, csq);
  k_prep    <<<dim3(16, 32, 16), 256, 0, stream>>>(z, flatT, zbf, ssq);
  k_rnorm   <<<64, 256, 0, stream>>>(ssq, rnorm);
  k_gemm    <<<dim3(NROW / 128, KC / 128), 256, 0, stream>>>(zbf, cb_bf, rnorm, csq,
                                                             (unsigned short*)S);
  k_softmax <<<NROW, 256, 0, stream>>>(S, cand_cnt, cand_list);
  k_fixup   <<<NROW, 64, 0, stream>>>(flatT, emb, cand_cnt, cand_list, idx);
  k_stats   <<<NROW, 256, 0, stream>>>(zbf, rnorm, idx, enc_sum, n_total, cl_part);
  k_nnew    <<<1, 256, 0, stream>>>(Nb, n_total, out_N, nw);
  k_zavg_emb<<<4096, 256, 0, stream>>>(za, enc_sum, out_N, nw, out_zav, out_emb, cbs_part);
  k_q       <<<32768, 256, 0, stream>>>(zbf, rnorm, idx, out);
  k_final   <<<1, 256, 0, stream>>>(cl_part, cbs_part, out);
}